// Round 6
// baseline (673.555 us; speedup 1.0000x reference)
//
#include <hip/hip_runtime.h>

#define TT 2048
#define HH 32
#define BB 512
#define SCL 2.8853900817779268f   // 2*log2(e): tanh(x) = 1 - 2/(2^(SCL*x)+1)

typedef float f32x2 __attribute__((ext_vector_type(2)));

#define PKFMA(acc, a, b) asm("v_pk_fma_f32 %0, %1, %2, %0" : "+v"(acc) : "v"(a), "v"(b))

__device__ __forceinline__ float tanh2(float s) {
    // s pre-scaled by SCL: tanh = 1 - 2/(exp2(s)+1)
    float e;
    asm("v_exp_f32 %0, %1" : "=v"(e) : "v"(s));
    float r = __builtin_amdgcn_rcpf(e + 1.0f);
    return fmaf(-2.0f, r, 1.0f);
}

__global__ __launch_bounds__(64) void rnn_fused(
    const float* __restrict__ x,      // [B, T, 1]
    const float* __restrict__ hid,    // [2, B, H]
    const float* __restrict__ W_ih0,  // [H, 1]
    const float* __restrict__ W_hh0,  // [H, H]
    const float* __restrict__ b_ih0,  // [H]
    const float* __restrict__ b_hh0,  // [H]
    const float* __restrict__ W_ih1,  // [H, H]
    const float* __restrict__ W_hh1,  // [H, H]
    const float* __restrict__ b_ih1,  // [H]
    const float* __restrict__ b_hh1,  // [H]
    const float* __restrict__ W_fc,   // [1, H]
    const float* __restrict__ b_fc,   // [1]
    float* __restrict__ out)          // [B*T] outs ++ [2*B*H] hidden
{
    const int lane   = (int)threadIdx.x;   // 0..63
    const int i      = lane & 31;          // unit index within the half
    const bool lower = lane < 32;          // lower: layer0 + fc; upper: layer1
    const int b      = (int)blockIdx.x;    // one batch per wave

    __shared__ __align__(16) float sh[64]; // [0..31] = h0, [32..63] = h1
    __shared__ float xs[32];               // current 32-step x window

    // ---- per-lane weights: unified instruction streams, per-half data ----
    const float* rowA = lower ? (W_hh0 + i * HH) : (W_ih1 + i * HH);
    const float* rowB = lower ? W_fc             : (W_hh1 + i * HH);
    const float  sclB = lower ? 1.0f : SCL;      // fc weights stay unscaled
    f32x2 wA[16], wB[16];
#pragma unroll
    for (int j = 0; j < 16; ++j) {
        wA[j] = f32x2{SCL * rowA[2 * j], SCL * rowA[2 * j + 1]};
        wB[j] = f32x2{sclB * rowB[2 * j], sclB * rowB[2 * j + 1]};
    }
    const float wx   = lower ? (SCL * W_ih0[i]) : 0.0f;
    const float bias = SCL * (lower ? (b_ih0[i] + b_hh0[i])
                                    : (b_ih1[i] + b_hh1[i]));
    const float sel  = lower ? 0.0f : 1.0f;
    const float bfc  = b_fc[0];

    // ---- initial hidden into LDS ----
    const float h_init = lower ? hid[b * HH + i] : hid[BB * HH + b * HH + i];
    sh[lane] = h_init;

    const float* xrow = x + b * TT;
    float* orow = out + b * TT;

    xs[i] = xrow[i];             // block 0 (both halves write same value)
    float xnxt = xrow[32 + i];   // block 1 prefetched in a register

    float hn = h_init;           // lower: current h0; upper: current h1

    // One pipelined step at iter tau: reads sh = {h0[tau-1], h1[tau-2]},
    // writes sh = {h0[tau], h1[tau-1]}, stores out[tau-2] = wfc.h1[tau-2]+bfc.
    auto STEP = [&](int kidx, bool do_store, int off) {
        float xv = xs[kidx];
        f32x2 A0 = {bias, 0.f}, A1 = {0.f, 0.f};
        f32x2 B0 = {0.f, 0.f},  B1 = {0.f, 0.f};
#pragma unroll
        for (int m = 0; m < 8; ++m) {
            float4 q = *(const float4*)&sh[4 * m];
            f32x2 qa = {q.x, q.y}, qb = {q.z, q.w};
            PKFMA(A0, wA[2 * m], qa);
            PKFMA(A1, wA[2 * m + 1], qb);
        }
#pragma unroll
        for (int m = 0; m < 8; ++m) {
            float4 q = *(const float4*)&sh[32 + 4 * m];
            f32x2 qa = {q.x, q.y}, qb = {q.z, q.w};
            PKFMA(B0, wB[2 * m], qa);
            PKFMA(B1, wB[2 * m + 1], qb);
        }
        f32x2 As = A0 + A1, Bs = B0 + B1;
        float s1 = As.x + As.y;
        float s2 = Bs.x + Bs.y;
        float pre = fmaf(sel, s2, fmaf(wx, xv, s1));
        float h = tanh2(pre);
        sh[lane] = h;
        hn = h;
        if (do_store && lane == 0) orow[off] = s2 + bfc;
    };

    // ===== tau = 0 peel: layer-0 only; upper half re-writes h1[-1] =====
    {
        float xv = xs[0];
        f32x2 A0 = {bias, 0.f}, A1 = {0.f, 0.f};
#pragma unroll
        for (int m = 0; m < 8; ++m) {
            float4 q = *(const float4*)&sh[4 * m];
            f32x2 qa = {q.x, q.y}, qb = {q.z, q.w};
            PKFMA(A0, wA[2 * m], qa);
            PKFMA(A1, wA[2 * m + 1], qb);
        }
        f32x2 As = A0 + A1;
        float h0new = tanh2(fmaf(wx, xv, As.x + As.y));
        float hw = lower ? h0new : h_init;   // preserve h1[-1] in upper half
        sh[lane] = hw;
        if (lower) hn = h0new;
    }

    // ===== block 0: tau = 1..31 (stores begin at tau = 2) =====
    for (int k = 1; k < 32; ++k) {
        STEP(k, k >= 2, k - 2);
    }
    xs[i] = xnxt;                 // rotate window to block 1
    xnxt = xrow[64 + i];          // prefetch block 2

    // ===== main: tau = 32..2047 =====
    for (int tb = 1; tb < 64; ++tb) {
        const int base = tb * 32;
#pragma unroll 4
        for (int k = 0; k < 32; ++k) {
            STEP(k, true, base + k - 2);
        }
        xs[i] = xnxt;
        int nidx = (tb + 2) * 32 + i;
        if (nidx >= TT) nidx = TT - 1;
        xnxt = xrow[nidx];
    }

    const float h0_fin = hn;      // lower lanes: h0[2047]

    // ===== epilogue tau = 2048: h1[2047] + out[2046] =====
    STEP(0, true, TT - 2);        // lower computes a discarded h0[2048]

    // ===== epilogue tau = 2049: out[2047] = wfc . h1[2047] + bfc =====
    {
        f32x2 B0 = {0.f, 0.f}, B1 = {0.f, 0.f};
#pragma unroll
        for (int m = 0; m < 8; ++m) {
            float4 q = *(const float4*)&sh[32 + 4 * m];
            f32x2 qa = {q.x, q.y}, qb = {q.z, q.w};
            PKFMA(B0, wB[2 * m], qa);
            PKFMA(B1, wB[2 * m + 1], qb);
        }
        f32x2 Bs = B0 + B1;
        if (lane == 0) orow[TT - 1] = (Bs.x + Bs.y) + bfc;
    }

    // ===== final hidden [2, B, H] =====
    if (lower) {
        out[BB * TT + b * HH + i] = h0_fin;            // h0[2047]
    } else {
        out[BB * TT + BB * HH + b * HH + i] = hn;      // h1[2047]
    }
}

extern "C" void kernel_launch(void* const* d_in, const int* in_sizes, int n_in,
                              void* d_out, int out_size, void* d_ws, size_t ws_size,
                              hipStream_t stream) {
    const float* xp    = (const float*)d_in[0];
    const float* hid   = (const float*)d_in[1];
    const float* Wih0  = (const float*)d_in[2];
    const float* Whh0  = (const float*)d_in[3];
    const float* bih0  = (const float*)d_in[4];
    const float* bhh0  = (const float*)d_in[5];
    const float* Wih1  = (const float*)d_in[6];
    const float* Whh1  = (const float*)d_in[7];
    const float* bih1  = (const float*)d_in[8];
    const float* bhh1  = (const float*)d_in[9];
    const float* Wfc   = (const float*)d_in[10];
    const float* bfc   = (const float*)d_in[11];
    float* outp        = (float*)d_out;

    rnn_fused<<<BB, 64, 0, stream>>>(xp, hid, Wih0, Whh0, bih0, bhh0,
                                     Wih1, Whh1, bih1, bhh1, Wfc, bfc, outp);
}

// Round 7
// 372.869 us; speedup vs baseline: 1.8064x; 1.8064x over previous
//
#include <hip/hip_runtime.h>

#define TT 2048
#define HH 32
#define BB 512
#define SCL 2.8853900817779268f   // 2*log2(e): tanh(x) = 1 - 2/(2^(SCL*x)+1)

typedef float f32x2 __attribute__((ext_vector_type(2)));

#define PKFMA(acc, a, b) asm("v_pk_fma_f32 %0, %1, %2, %0" : "+v"(acc) : "v"(a), "v"(b))

__device__ __forceinline__ float tanh2(float s) {
    // s pre-scaled by SCL: tanh = 1 - 2/(exp2(s)+1)
    float e;
    asm("v_exp_f32 %0, %1" : "=v"(e) : "v"(s));
    float r = __builtin_amdgcn_rcpf(e + 1.0f);
    return fmaf(-2.0f, r, 1.0f);
}

__global__ __launch_bounds__(64) void rnn_fused(
    const float* __restrict__ x,      // [B, T, 1]
    const float* __restrict__ hid,    // [2, B, H]
    const float* __restrict__ W_ih0,  // [H, 1]
    const float* __restrict__ W_hh0,  // [H, H]
    const float* __restrict__ b_ih0,  // [H]
    const float* __restrict__ b_hh0,  // [H]
    const float* __restrict__ W_ih1,  // [H, H]
    const float* __restrict__ W_hh1,  // [H, H]
    const float* __restrict__ b_ih1,  // [H]
    const float* __restrict__ b_hh1,  // [H]
    const float* __restrict__ W_fc,   // [1, H]
    const float* __restrict__ b_fc,   // [1]
    float* __restrict__ out)          // [B*T] outs ++ [2*B*H] hidden
{
    const int lane   = (int)threadIdx.x;   // 0..63
    const int i      = lane & 31;          // unit index within the half
    const bool lower = lane < 32;          // lower: layer0 + fc; upper: layer1
    const int b      = (int)blockIdx.x;    // one batch per wave

    __shared__ __align__(16) float sh[64]; // [0..31] = h0, [32..63] = h1
    __shared__ float xs[32];               // current 32-step x window

    // ---- per-lane weights: unified instruction streams, per-half data ----
    const float* rowA = lower ? (W_hh0 + i * HH) : (W_ih1 + i * HH);
    const float* rowB = lower ? W_fc             : (W_hh1 + i * HH);
    const float  sclB = lower ? 1.0f : SCL;      // fc weights stay unscaled
    f32x2 wA[16], wB[16];
#pragma unroll
    for (int j = 0; j < 16; ++j) {
        wA[j] = f32x2{SCL * rowA[2 * j], SCL * rowA[2 * j + 1]};
        wB[j] = f32x2{sclB * rowB[2 * j], sclB * rowB[2 * j + 1]};
    }
    const float wx   = lower ? (SCL * W_ih0[i]) : 0.0f;
    const float bias = SCL * (lower ? (b_ih0[i] + b_hh0[i])
                                    : (b_ih1[i] + b_hh1[i]));
    const float sel  = lower ? 0.0f : 1.0f;
    const float bfc  = b_fc[0];

    // ---- initial hidden into LDS ----
    const float h_init = lower ? hid[b * HH + i] : hid[BB * HH + b * HH + i];
    sh[lane] = h_init;

    const float* xrow = x + b * TT;
    float* orow = out + b * TT;

    xs[i] = xrow[i];             // block 0 (both halves write same value)
    float xnxt = xrow[32 + i];   // block 1 prefetched in a register

    float hn = h_init;           // lower: current h0; upper: current h1

    // persistent register image of sh: q[0..7] = h0-half, q[8..15] = h1-half
    float4 q[16];
    auto LOADQ = [&]() {
#pragma unroll
        for (int m = 0; m < 16; ++m) q[m] = *(const float4*)&sh[4 * m];
    };
    LOADQ();                     // q = {h0[-1], h1[-1]}

    // One pipelined step at iter tau: q holds {h0[tau-1], h1[tau-2]}.
    // Computes h0[tau] (lower) / h1[tau-1] (upper), stores out[tau-2],
    // writes sh, and re-loads q for the next step.
    auto STEP = [&](int kidx, bool do_store, int off) {
        float xv = xs[kidx];
        f32x2 A0 = {bias, 0.f}, A1 = {0.f, 0.f};
        f32x2 B0 = {0.f, 0.f},  B1 = {0.f, 0.f};
#pragma unroll
        for (int m = 0; m < 8; ++m) {
            f32x2 qa = {q[m].x, q[m].y}, qb = {q[m].z, q[m].w};
            PKFMA(A0, wA[2 * m], qa);
            PKFMA(A1, wA[2 * m + 1], qb);
        }
#pragma unroll
        for (int m = 0; m < 8; ++m) {
            f32x2 qa = {q[8 + m].x, q[8 + m].y}, qb = {q[8 + m].z, q[8 + m].w};
            PKFMA(B0, wB[2 * m], qa);
            PKFMA(B1, wB[2 * m + 1], qb);
        }
        f32x2 As = A0 + A1, Bs = B0 + B1;
        float s1 = As.x + As.y;
        float s2 = Bs.x + Bs.y;
        float pre = fmaf(sel, s2, fmaf(wx, xv, s1));
        float h = tanh2(pre);
        sh[lane] = h;
        hn = h;
        if (do_store && lane == 0) orow[off] = s2 + bfc;
        LOADQ();                 // reads follow the write -> see fresh values
    };

    // ===== tau = 0 peel: layer-0 only; upper half re-writes h1[-1] =====
    {
        float xv = xs[0];
        f32x2 A0 = {bias, 0.f}, A1 = {0.f, 0.f};
#pragma unroll
        for (int m = 0; m < 8; ++m) {
            f32x2 qa = {q[m].x, q[m].y}, qb = {q[m].z, q[m].w};
            PKFMA(A0, wA[2 * m], qa);
            PKFMA(A1, wA[2 * m + 1], qb);
        }
        f32x2 As = A0 + A1;
        float h0new = tanh2(fmaf(wx, xv, As.x + As.y));
        float hw = lower ? h0new : h_init;   // preserve h1[-1] in upper half
        sh[lane] = hw;
        if (lower) hn = h0new;
        LOADQ();                 // q = {h0[0], h1[-1]}
    }

    // ===== block 0: tau = 1..31 (stores begin at tau = 2) =====
#pragma unroll
    for (int k = 1; k < 32; ++k) {
        STEP(k, k >= 2, k - 2);
    }
    xs[i] = xnxt;                 // rotate window to block 1
    xnxt = xrow[64 + i];          // prefetch block 2

    // ===== main: tau = 32..2047 =====
    for (int tb = 1; tb < 64; ++tb) {
        const int base = tb * 32;
#pragma unroll
        for (int k = 0; k < 32; ++k) {
            STEP(k, true, base + k - 2);
        }
        xs[i] = xnxt;
        int nidx = (tb + 2) * 32 + i;
        if (nidx >= TT) nidx = TT - 1;
        xnxt = xrow[nidx];
    }

    const float h0_fin = hn;      // lower lanes: h0[2047]

    // ===== epilogue tau = 2048: h1[2047] + out[2046] =====
    STEP(0, true, TT - 2);        // lower computes a discarded h0[2048]

    // ===== epilogue tau = 2049: out[2047] = wfc . h1[2047] + bfc =====
    {
        f32x2 B0 = {0.f, 0.f}, B1 = {0.f, 0.f};
#pragma unroll
        for (int m = 0; m < 8; ++m) {
            f32x2 qa = {q[8 + m].x, q[8 + m].y}, qb = {q[8 + m].z, q[8 + m].w};
            PKFMA(B0, wB[2 * m], qa);
            PKFMA(B1, wB[2 * m + 1], qb);
        }
        f32x2 Bs = B0 + B1;
        if (lane == 0) orow[TT - 1] = (Bs.x + Bs.y) + bfc;
    }

    // ===== final hidden [2, B, H] =====
    if (lower) {
        out[BB * TT + b * HH + i] = h0_fin;            // h0[2047]
    } else {
        out[BB * TT + BB * HH + b * HH + i] = hn;      // h1[2047]
    }
}

extern "C" void kernel_launch(void* const* d_in, const int* in_sizes, int n_in,
                              void* d_out, int out_size, void* d_ws, size_t ws_size,
                              hipStream_t stream) {
    const float* xp    = (const float*)d_in[0];
    const float* hid   = (const float*)d_in[1];
    const float* Wih0  = (const float*)d_in[2];
    const float* Whh0  = (const float*)d_in[3];
    const float* bih0  = (const float*)d_in[4];
    const float* bhh0  = (const float*)d_in[5];
    const float* Wih1  = (const float*)d_in[6];
    const float* Whh1  = (const float*)d_in[7];
    const float* bih1  = (const float*)d_in[8];
    const float* bhh1  = (const float*)d_in[9];
    const float* Wfc   = (const float*)d_in[10];
    const float* bfc   = (const float*)d_in[11];
    float* outp        = (float*)d_out;

    rnn_fused<<<BB, 64, 0, stream>>>(xp, hid, Wih0, Whh0, bih0, bhh0,
                                     Wih1, Whh1, bih1, bhh1, Wfc, bfc, outp);
}